// Round 10
// baseline (189.984 us; speedup 1.0000x reference)
//
#include <hip/hip_runtime.h>

// ---------------------------------------------------------------------------
// Self-attention (B=4, N=2048, D=1024) on MI355X — fp16, round 10:
// round-8 pipeline with gemm2 at BK=32 / 32 KB LDS -> 4 blocks/CU
// (m97/m114 occupancy-overlap regime). Counted vmcnt(4), raw barriers,
// BK=32 swizzle slot^=(row>>1)&3 (2-way, free), T1 XCD remap, T5 setprio.
// All plain fp16 (round-8 numerics, absmax floor 4.88e-4).
// ---------------------------------------------------------------------------

typedef _Float16 hfx8 __attribute__((ext_vector_type(8)));
typedef _Float16 hfx4 __attribute__((ext_vector_type(4)));
typedef float fx4 __attribute__((ext_vector_type(4)));

__device__ __forceinline__ void load_lds16(const void* g, void* l) {
    __builtin_amdgcn_global_load_lds(
        (const __attribute__((address_space(1))) void*)g,
        (__attribute__((address_space(3))) void*)l, 16, 0, 0);
}

template <int N> __device__ __forceinline__ void vmwait() {
    if constexpr (N == 8) asm volatile("s_waitcnt vmcnt(8)" ::: "memory");
    else if constexpr (N == 4) asm volatile("s_waitcnt vmcnt(4)" ::: "memory");
    else asm volatile("s_waitcnt vmcnt(0)" ::: "memory");
}

// bijective XCD-chunked grid remap (T1, m204). Requires nwg % 8 == 0.
__device__ __forceinline__ void xcd_remap(int& x, int& y, int& z) {
    const int gx = gridDim.x, gy = gridDim.y;
    const int lin = blockIdx.x + gx * (blockIdx.y + gy * blockIdx.z);
    const int cpx = (gx * gy * gridDim.z) >> 3;
    const int w = (lin & 7) * cpx + (lin >> 3);
    x = w % gx;
    y = (w / gx) % gy;
    z = w / (gx * gy);
}

// ---------------------------------------------------------------------------
__global__ __launch_bounds__(256) void convx_kernel(
    const float4* __restrict__ in, _Float16* __restrict__ out)
{
    const int i = blockIdx.x * 256 + threadIdx.x;
    float4 v = in[i];
    hfx4 h;
    h[0] = (_Float16)v.x; h[1] = (_Float16)v.y;
    h[2] = (_Float16)v.z; h[3] = (_Float16)v.w;
    *(hfx4*)&out[(long)i * 4] = h;
}

__global__ __launch_bounds__(256) void convw3_kernel(
    const float4* __restrict__ w0, const float4* __restrict__ w1, const float4* __restrict__ w2,
    _Float16* __restrict__ o0, _Float16* __restrict__ o1, _Float16* __restrict__ o2)
{
    const int wsel = blockIdx.x >> 10;
    const float4* in = wsel == 0 ? w0 : (wsel == 1 ? w1 : w2);
    _Float16* out = wsel == 0 ? o0 : (wsel == 1 ? o1 : o2);
    const int i = (blockIdx.x & 1023) * 256 + threadIdx.x;
    float4 v = in[i];
    hfx4 h;
    h[0] = (_Float16)v.x; h[1] = (_Float16)v.y;
    h[2] = (_Float16)v.z; h[3] = (_Float16)v.w;
    *(hfx4*)&out[(long)i * 4] = h;
}

// ---------------------------------------------------------------------------
// 2-phase pipelined GEMM, BK=32 / 32 KB LDS -> 4 blocks/CU.
// BM=BN=128, 256 thr = 4 waves (2x2). Counted-vmcnt double-buffer, raw
// s_barrier only. Swizzle (both sides): 16B-slot ^= (row>>1)&3 -> 2-way.
// A [M x K] row-major lda; B [N x K] row-major ldb.
// OMODE 0: fp32 out = alpha*acc -> outF + z*sCz (ldc); B = Bq + z*sBz
// OMODE 1: projections (K=1024): z=0 Q fp16 [8192][1024], z=1 K fp16,
//          z=2 V transposed [4][1024][2048]
// ---------------------------------------------------------------------------
template <int OMODE>
__global__ __launch_bounds__(256, 4) void gemm2(
    const _Float16* __restrict__ A,
    const _Float16* __restrict__ Bq, const _Float16* __restrict__ Bk, const _Float16* __restrict__ Bv,
    const float* __restrict__ bq, const float* __restrict__ bk, const float* __restrict__ bv,
    float* __restrict__ outF, _Float16* __restrict__ oQ, _Float16* __restrict__ oK, _Float16* __restrict__ oV,
    int K, int lda, int ldb, int ldc, float alpha,
    long sAz, long sBz, long sCz)
{
    constexpr int BM = 128, BN = 128, BK = 32;
    constexpr int LPT = 4;   // global_load_lds per thread per K-tile

    __shared__ __attribute__((aligned(16))) _Float16 lds[2][(BM + BN) * BK]; // 32 KB

    int bx, by, z;
    xcd_remap(bx, by, z);

    A += (long)z * sAz;
    const _Float16* B = (OMODE == 1) ? (z == 0 ? Bq : (z == 1 ? Bk : Bv))
                                     : Bq + (long)z * sBz;

    const int tid = threadIdx.x;
    const int lane = tid & 63;
    const int wv = tid >> 6;
    const int wr = wv >> 1, wc = wv & 1;   // 2x2 wave grid, 64x64 out each
    const int lr = lane & 15, lk = lane >> 4;

    const long m0 = (long)by * BM;
    const long n0 = (long)bx * BN;

    fx4 acc[4][4] = {};

    // stage K-tile at element offset kt into buffer b. Linear LDS dest;
    // global source col pre-swizzled by the read involution (rule #21):
    // 16B-slot ^= (row>>1)&3.
    auto STAGE = [&](int kt, int b) {
#pragma unroll
        for (int i = 0; i < LPT; ++i) {
            const int c = i * 256 + tid;
            if (i < 2) {                    // A: 128 rows x 4 slots
                const int row = c >> 2, slot = c & 3;
                load_lds16(A + (m0 + row) * (long)lda + kt + ((slot ^ ((row >> 1) & 3)) << 3),
                           &lds[b][row * 32 + slot * 8]);
            } else {                        // B
                const int c2 = c - 512;
                const int row = c2 >> 2, slot = c2 & 3;
                load_lds16(B + (n0 + row) * (long)ldb + kt + ((slot ^ ((row >> 1) & 3)) << 3),
                           &lds[b][BM * BK + row * 32 + slot * 8]);
            }
        }
    };

    const int NT = K / BK;
    STAGE(0, 0);
    STAGE(BK, 1);
    vmwait<4>();                            // tile 0 landed, tile 1 in flight
    __builtin_amdgcn_s_barrier();
    __builtin_amdgcn_sched_barrier(0);

    const int rA0 = wr * 64 + lr;
    const int rB0 = wc * 64 + lr;
    const int eA = (((rA0 >> 1) & 3) << 3); // row bits 1-2 invariant under +16q
    const int eB = (((rB0 >> 1) & 3) << 3);

    for (int t = 0; t < NT; ++t) {
        const _Float16* LA = &lds[t & 1][0];
        const _Float16* LB = LA + BM * BK;

        hfx8 bfr[4];
#pragma unroll
        for (int nf = 0; nf < 4; ++nf)
            bfr[nf] = *(const hfx8*)&LB[(rB0 + nf * 16) * BK + ((lk * 8) ^ eB)];

#pragma unroll
        for (int q = 0; q < 4; ++q) {
            hfx8 afr = *(const hfx8*)&LA[(rA0 + q * 16) * BK + ((lk * 8) ^ eA)];
            __builtin_amdgcn_s_setprio(1);
#pragma unroll
            for (int nf = 0; nf < 4; ++nf)
                acc[q][nf] = __builtin_amdgcn_mfma_f32_16x16x32_f16(
                    afr, bfr[nf], acc[q][nf], 0, 0, 0);
            __builtin_amdgcn_s_setprio(0);
        }

        __builtin_amdgcn_s_barrier();       // all waves done reading buf (t&1)
        if (t + 2 < NT) {
            STAGE((t + 2) * BK, t & 1);     // refill just-freed buffer
            vmwait<4>();                    // tile t+1 landed; t+2 in flight
        } else {
            vmwait<0>();                    // tail drain
        }
        __builtin_amdgcn_s_barrier();       // all waves see tile t+1 landed
        __builtin_amdgcn_sched_barrier(0);
    }

    // epilogue. D frag: col = lane&15, row = lk*4 + j
#pragma unroll
    for (int mf = 0; mf < 4; ++mf) {
#pragma unroll
        for (int nf = 0; nf < 4; ++nf) {
            const long row0 = m0 + wr * 64 + mf * 16 + lk * 4;
            const long col = n0 + wc * 64 + nf * 16 + lr;
            if constexpr (OMODE == 0) {
                float* oz = outF + (long)z * sCz;
#pragma unroll
                for (int j = 0; j < 4; ++j)
                    oz[(row0 + j) * (long)ldc + col] = alpha * acc[mf][nf][j];
            } else {
                if (z == 0) {
                    const float bb = bq[col];
#pragma unroll
                    for (int j = 0; j < 4; ++j)
                        oQ[(row0 + j) * 1024 + col] = (_Float16)(acc[mf][nf][j] + bb);
                } else if (z == 1) {
                    const float bb = bk[col];
#pragma unroll
                    for (int j = 0; j < 4; ++j)
                        oK[(row0 + j) * 1024 + col] = (_Float16)(acc[mf][nf][j] + bb);
                } else {
                    const float bb = bv[col];
                    hfx4 pk;
#pragma unroll
                    for (int j = 0; j < 4; ++j) pk[j] = (_Float16)(acc[mf][nf][j] + bb);
                    *(hfx4*)&oV[((row0 >> 11) * 1024 + col) * 2048 + (row0 & 2047)] = pk;
                }
            }
        }
    }
}

// ---------------------------------------------------------------------------
// Row softmax over 2048 fp32, write fp16 probs IN PLACE. One block per row.
// ---------------------------------------------------------------------------
__global__ __launch_bounds__(256) void softmax_kernel(float* __restrict__ S)
{
    const long row = blockIdx.x;
    float* r = S + row * 2048;
    const int t = threadIdx.x;

    float4 v0 = *(const float4*)&r[t * 4];
    float4 v1 = *(const float4*)&r[1024 + t * 4];
    float v[8] = {v0.x, v0.y, v0.z, v0.w, v1.x, v1.y, v1.z, v1.w};

    float mx = v[0];
#pragma unroll
    for (int j = 1; j < 8; ++j) mx = fmaxf(mx, v[j]);
#pragma unroll
    for (int o = 32; o; o >>= 1) mx = fmaxf(mx, __shfl_xor(mx, o, 64));

    __shared__ float redm[4];
    __shared__ float reds[4];
    const int w = t >> 6;
    if ((t & 63) == 0) redm[w] = mx;
    __syncthreads();
    mx = fmaxf(fmaxf(redm[0], redm[1]), fmaxf(redm[2], redm[3]));

    float e[8];
    float s = 0.f;
#pragma unroll
    for (int j = 0; j < 8; ++j) {
        e[j] = __expf(v[j] - mx);
        s += e[j];
    }
#pragma unroll
    for (int o = 32; o; o >>= 1) s += __shfl_xor(s, o, 64);
    if ((t & 63) == 0) reds[w] = s;
    __syncthreads();
    s = reds[0] + reds[1] + reds[2] + reds[3];

    const float inv = 1.0f / s;
    hfx4 p0, p1;
#pragma unroll
    for (int j = 0; j < 4; ++j) {
        p0[j] = (_Float16)(e[j] * inv);
        p1[j] = (_Float16)(e[4 + j] * inv);
    }
    _Float16* pr = (_Float16*)r;
    *(hfx4*)&pr[t * 4] = p0;
    *(hfx4*)&pr[1024 + t * 4] = p1;
}

// ---------------------------------------------------------------------------
extern "C" void kernel_launch(void* const* d_in, const int* in_sizes, int n_in,
                              void* d_out, int out_size, void* d_ws, size_t ws_size,
                              hipStream_t stream)
{
    const float* x  = (const float*)d_in[0];
    const float* Wq = (const float*)d_in[1];
    const float* bq = (const float*)d_in[2];
    const float* Wk = (const float*)d_in[3];
    const float* bk = (const float*)d_in[4];
    const float* Wv = (const float*)d_in[5];
    const float* bv = (const float*)d_in[6];
    float* out = (float*)d_out;

    _Float16* xs  = (_Float16*)d_ws;            // [8192][1024] 16 MB
    _Float16* Wqh = xs + 8192ull * 1024;        // [1024][1024] 2 MB each
    _Float16* Wkh = Wqh + 1024ull * 1024;
    _Float16* Wvh = Wkh + 1024ull * 1024;
    _Float16* Qp  = Wvh + 1024ull * 1024;       // [8192][1024] 16 MB
    _Float16* Ks  = Qp + 8192ull * 1024;        // [8192][1024] 16 MB
    _Float16* Vt  = Ks + 8192ull * 1024;        // [4][1024][2048] 16 MB
    float* S      = (float*)(Vt + 4ull * 1024 * 2048);  // [4][2048][2048] 64 MB

    dim3 blk(256);

    // 1) converts (plain fp16)
    convx_kernel<<<8192, blk, 0, stream>>>((const float4*)x, xs);
    convw3_kernel<<<3072, blk, 0, stream>>>(
        (const float4*)Wq, (const float4*)Wk, (const float4*)Wv, Wqh, Wkh, Wvh);

    // 2) projections: 8 x 64 x 3 = 1536 blocks, K=1024 plain for Q, K, V.
    gemm2<1><<<dim3(8, 64, 3), blk, 0, stream>>>(
        xs, Wqh, Wkh, Wvh, bq, bk, bv,
        nullptr, Qp, Ks, Vt,
        1024, 1024, 1024, 0, 1.0f, 0L, 0L, 0L);

    // 3) scores: Q @ K^T plain (K=1024), fp32 out, z=4  (16x16x4 = 1024 blocks)
    gemm2<0><<<dim3(16, 16, 4), blk, 0, stream>>>(
        Qp, Ks, nullptr, nullptr, nullptr, nullptr, nullptr,
        S, nullptr, nullptr, nullptr,
        1024, 1024, 1024, 2048, 1.0f,
        2097152L, 2097152L, 4194304L);

    // 4) softmax (P fp16 in place)
    softmax_kernel<<<2048 * 4, blk, 0, stream>>>(S);

    // 5) PV: P @ Vt^T, alpha = 1/32, fp32 out, z=4  (8x16x4 = 512 blocks)
    gemm2<0><<<dim3(8, 16, 4), blk, 0, stream>>>(
        (const _Float16*)S, Vt, nullptr, nullptr, nullptr, nullptr, nullptr,
        out, nullptr, nullptr, nullptr,
        2048, 4096, 2048, 1024, 0.03125f,
        8388608L, 2097152L, 2097152L);
}